// Round 1
// baseline (1230.920 us; speedup 1.0000x reference)
//
#include <hip/hip_runtime.h>
#include <math.h>

#define DEVINL __device__ __forceinline__

DEVINL float sigmoidf_(float x) { return 1.0f / (1.0f + expf(-x)); }

// ---------------------------------------------------------------------------
// k1: conv 1->4 (5x5, same) + relu + 2x2 maxpool
//     obs (256,1,256,256) -> out (256,4,128,128)
// one thread per pooled output pixel; 6x6 input patch in registers
// ---------------------------------------------------------------------------
__global__ __launch_bounds__(256) void k1_conv_pool(
    const float* __restrict__ obs, const float* __restrict__ w1,
    const float* __restrict__ b1, float* __restrict__ out)
{
    unsigned gid = blockIdx.x * 256u + threadIdx.x;
    int x  = gid & 127;
    int y  = (gid >> 7) & 127;
    int oc = (blockIdx.x >> 6) & 3;   // uniform per block
    int tb = blockIdx.x >> 8;         // uniform per block

    const float* in = obs + ((size_t)tb << 16);  // 256*256 per image
    int iy0 = 2 * y - 2, ix0 = 2 * x - 2;

    float p[6][6];
    #pragma unroll
    for (int r = 0; r < 6; ++r) {
        int iy = iy0 + r;
        bool yok = (unsigned)iy < 256u;
        #pragma unroll
        for (int c = 0; c < 6; ++c) {
            int ix = ix0 + c;
            p[r][c] = (yok && (unsigned)ix < 256u) ? in[(iy << 8) + ix] : 0.f;
        }
    }

    const float* w = w1 + oc * 25;
    float wv[25];
    #pragma unroll
    for (int k = 0; k < 25; ++k) wv[k] = w[k];
    float bias = b1[oc];

    float m = 0.f;  // relu floor, so max-with-0 == relu+max
    #pragma unroll
    for (int pp = 0; pp < 2; ++pp)
    #pragma unroll
    for (int q = 0; q < 2; ++q) {
        float acc = bias;
        #pragma unroll
        for (int ky = 0; ky < 5; ++ky)
        #pragma unroll
        for (int kx = 0; kx < 5; ++kx)
            acc = fmaf(p[pp + ky][q + kx], wv[ky * 5 + kx], acc);
        m = fmaxf(m, acc);
    }
    out[gid] = m;  // gid == (tb,oc,y,x) linear
}

// ---------------------------------------------------------------------------
// k2: conv 4->4 (5x5, same) + relu + 2x2 maxpool
//     in (256,4,128,128) -> out (256,4,64,64)
// ---------------------------------------------------------------------------
__global__ __launch_bounds__(256) void k2_conv_pool(
    const float* __restrict__ in, const float* __restrict__ w2,
    const float* __restrict__ b2, float* __restrict__ out)
{
    unsigned gid = blockIdx.x * 256u + threadIdx.x;
    int x  = gid & 63;
    int y  = (gid >> 6) & 63;
    int oc = (blockIdx.x >> 4) & 3;   // uniform
    int tb = blockIdx.x >> 6;         // uniform

    float bias = b2[oc];
    float acc[2][2] = {{bias, bias}, {bias, bias}};
    int iy0 = 2 * y - 2, ix0 = 2 * x - 2;

    for (int ic = 0; ic < 4; ++ic) {
        const float* base = in + (((size_t)tb * 4 + ic) << 14);  // 128*128
        float p[6][6];
        #pragma unroll
        for (int r = 0; r < 6; ++r) {
            int iy = iy0 + r;
            bool yok = (unsigned)iy < 128u;
            #pragma unroll
            for (int c = 0; c < 6; ++c) {
                int ix = ix0 + c;
                p[r][c] = (yok && (unsigned)ix < 128u) ? base[(iy << 7) + ix] : 0.f;
            }
        }
        const float* w = w2 + (oc * 4 + ic) * 25;
        float wv[25];
        #pragma unroll
        for (int k = 0; k < 25; ++k) wv[k] = w[k];
        #pragma unroll
        for (int pp = 0; pp < 2; ++pp)
        #pragma unroll
        for (int q = 0; q < 2; ++q) {
            #pragma unroll
            for (int ky = 0; ky < 5; ++ky)
            #pragma unroll
            for (int kx = 0; kx < 5; ++kx)
                acc[pp][q] = fmaf(p[pp + ky][q + kx], wv[ky * 5 + kx], acc[pp][q]);
        }
    }

    float m = 0.f;
    #pragma unroll
    for (int pp = 0; pp < 2; ++pp)
    #pragma unroll
    for (int q = 0; q < 2; ++q)
        m = fmaxf(m, acc[pp][q]);
    out[gid] = m;
}

// ---------------------------------------------------------------------------
// k3: conv 4->32 (5x5, same) input-gate precompute
//     in (256,4,64,64) -> out (256,32,64,64)
// ---------------------------------------------------------------------------
__global__ __launch_bounds__(256) void k3_convx(
    const float* __restrict__ in, const float* __restrict__ wx,
    const float* __restrict__ bx, float* __restrict__ out)
{
    unsigned gid = blockIdx.x * 256u + threadIdx.x;
    int x  = gid & 63;
    int y  = (gid >> 6) & 63;
    int oc = (blockIdx.x >> 4) & 31;  // uniform
    int tb = blockIdx.x >> 9;         // uniform

    float acc = bx[oc];
    for (int ic = 0; ic < 4; ++ic) {
        const float* base = in + (((size_t)tb * 4 + ic) << 12);  // 64*64
        const float* w = wx + (oc * 4 + ic) * 25;
        #pragma unroll
        for (int ky = 0; ky < 5; ++ky) {
            int iy = y + ky - 2;
            bool yok = (unsigned)iy < 64u;
            #pragma unroll
            for (int kx = 0; kx < 5; ++kx) {
                int ix = x + kx - 2;
                float v = (yok && (unsigned)ix < 64u) ? base[(iy << 6) + ix] : 0.f;
                acc = fmaf(v, w[ky * 5 + kx], acc);
            }
        }
    }
    out[gid] = acc;
}

// ---------------------------------------------------------------------------
// k4: one ConvLSTM step.
//     xg_t (32,32,64,64), h_in/c_in (32,8,64,64), wh (32,8,5,5)
//     thread = (b, ch, y, x); computes all 4 gates for its (ch,pixel).
//     c updated in place is safe (pure Hadamard on c).
// ---------------------------------------------------------------------------
__global__ __launch_bounds__(256) void k4_lstm_step(
    const float* __restrict__ xg_t, const float* __restrict__ h_in,
    const float* __restrict__ c_in, const float* __restrict__ wh,
    const float* __restrict__ bh, const float* __restrict__ wci,
    const float* __restrict__ wcf, const float* __restrict__ wco,
    float* __restrict__ h_out, float* __restrict__ c_out)
{
    unsigned gid = blockIdx.x * 256u + threadIdx.x;
    int x  = gid & 63;
    int y  = (gid >> 6) & 63;
    int ch = (blockIdx.x >> 4) & 7;   // uniform
    int b  = blockIdx.x >> 7;         // uniform
    int pix = (y << 6) + x;

    float acc[4];
    #pragma unroll
    for (int g = 0; g < 4; ++g)
        acc[g] = bh[g * 8 + ch] +
                 xg_t[(((size_t)b * 32 + g * 8 + ch) << 12) + pix];

    for (int ic = 0; ic < 8; ++ic) {
        const float* base = h_in + (((size_t)b * 8 + ic) << 12);
        float p[25];
        #pragma unroll
        for (int ky = 0; ky < 5; ++ky) {
            int iy = y + ky - 2;
            bool yok = (unsigned)iy < 64u;
            #pragma unroll
            for (int kx = 0; kx < 5; ++kx) {
                int ix = x + kx - 2;
                p[ky * 5 + kx] =
                    (yok && (unsigned)ix < 64u) ? base[(iy << 6) + ix] : 0.f;
            }
        }
        #pragma unroll
        for (int g = 0; g < 4; ++g) {
            const float* w = wh + ((g * 8 + ch) * 8 + ic) * 25;  // uniform
            #pragma unroll
            for (int k = 0; k < 25; ++k)
                acc[g] = fmaf(p[k], w[k], acc[g]);
        }
    }

    size_t idx = (((size_t)b * 8 + ch) << 12) + pix;
    int pidx = (ch << 12) + pix;
    float c_old = c_in[idx];
    float i = sigmoidf_(acc[0] + c_old * wci[pidx]);
    float f = sigmoidf_(acc[1] + c_old * wcf[pidx]);
    float c_new = f * c_old + i * tanhf(acc[2]);
    float o = sigmoidf_(acc[3] + c_new * wco[pidx]);
    h_out[idx] = o * tanhf(c_new);
    c_out[idx] = c_new;
}

// ---------------------------------------------------------------------------
extern "C" void kernel_launch(void* const* d_in, const int* in_sizes, int n_in,
                              void* d_out, int out_size, void* d_ws, size_t ws_size,
                              hipStream_t stream)
{
    const float* obs = (const float*)d_in[0];
    const float* w1  = (const float*)d_in[1];
    const float* b1  = (const float*)d_in[2];
    const float* w2  = (const float*)d_in[3];
    const float* b2  = (const float*)d_in[4];
    const float* wx  = (const float*)d_in[5];
    const float* bx  = (const float*)d_in[6];
    const float* wh  = (const float*)d_in[7];
    const float* bh  = (const float*)d_in[8];
    const float* wci = (const float*)d_in[9];
    const float* wcf = (const float*)d_in[10];
    const float* wco = (const float*)d_in[11];

    float* ws = (float*)d_ws;
    // layout (floats):
    //   [0, 16.7M)        s1 (256,4,128,128)   -- dead after k2
    //   [0, 33.5M)        xg (8,32,32,64,64)   -- overlays s1 (written by k3)
    //   [33.5M, 37.7M)    s2 (256,4,64,64)
    //   [37.7M, ...)      h0, h1, c   (each 1,048,576)
    float* s1 = ws;
    float* xg = ws;
    float* s2 = ws + 33554432;
    float* h0 = ws + 37748736;
    float* h1 = h0 + 1048576;
    float* cc = h1 + 1048576;

    k1_conv_pool<<<65536, 256, 0, stream>>>(obs, w1, b1, s1);
    k2_conv_pool<<<16384, 256, 0, stream>>>(s1, w2, b2, s2);
    k3_convx   <<<131072, 256, 0, stream>>>(s2, wx, bx, xg);

    hipMemsetAsync(h0, 0, (size_t)1048576 * 4, stream);
    hipMemsetAsync(cc, 0, (size_t)1048576 * 4, stream);

    float* hb[2] = {h0, h1};
    for (int t = 0; t < 8; ++t) {
        const float* h_in = hb[t & 1];
        float* h_out = (t == 7) ? (float*)d_out : hb[(t + 1) & 1];
        float* c_out = (t == 7) ? ((float*)d_out + 1048576) : cc;
        k4_lstm_step<<<4096, 256, 0, stream>>>(
            xg + (size_t)t * 4194304, h_in, cc, wh, bh, wci, wcf, wco,
            h_out, c_out);
    }
}

// Round 2
// 639.903 us; speedup vs baseline: 1.9236x; 1.9236x over previous
//
#include <hip/hip_runtime.h>
#include <math.h>

#define DEVINL __device__ __forceinline__

DEVINL float sigmoidf_(float x) { return 1.0f / (1.0f + expf(-x)); }

// ---------------------------------------------------------------------------
// k1: conv 1->4 (5x5, same) + relu + 2x2 maxpool
//     obs (256,1,256,256) -> out (256,4,128,128)
// thread = pooled pixel; computes ALL 4 output channels from one 6x6 patch
// ---------------------------------------------------------------------------
__global__ __launch_bounds__(256) void k1_conv_pool(
    const float* __restrict__ obs, const float* __restrict__ w1,
    const float* __restrict__ b1, float* __restrict__ out)
{
    unsigned gid = blockIdx.x * 256u + threadIdx.x;
    int pix = gid & 16383;          // 128*128
    int x = pix & 127;
    int y = pix >> 7;
    int tb = blockIdx.x >> 6;       // uniform per block

    const float* in = obs + ((size_t)tb << 16);
    int iy0 = 2 * y - 2, ix0 = 2 * x - 2;

    float p[6][6];
    #pragma unroll
    for (int r = 0; r < 6; ++r) {
        int iy = iy0 + r;
        bool yok = (unsigned)iy < 256u;
        #pragma unroll
        for (int c = 0; c < 6; ++c) {
            int ix = ix0 + c;
            p[r][c] = (yok && (unsigned)ix < 256u) ? in[(iy << 8) + ix] : 0.f;
        }
    }

    #pragma unroll
    for (int oc = 0; oc < 4; ++oc) {
        const float* w = w1 + oc * 25;     // grid-uniform -> s_load
        float bias = b1[oc];
        float m = 0.f;                     // relu floor
        #pragma unroll
        for (int pp = 0; pp < 2; ++pp)
        #pragma unroll
        for (int q = 0; q < 2; ++q) {
            float acc = bias;
            #pragma unroll
            for (int ky = 0; ky < 5; ++ky)
            #pragma unroll
            for (int kx = 0; kx < 5; ++kx)
                acc = fmaf(p[pp + ky][q + kx], w[ky * 5 + kx], acc);
            m = fmaxf(m, acc);
        }
        out[(((size_t)tb * 4 + oc) << 14) + pix] = m;
    }
}

// ---------------------------------------------------------------------------
// k2: conv 4->4 (5x5, same) + relu + 2x2 maxpool
//     in (256,4,128,128) -> out (256,4,64,64)
// thread = pooled pixel; all 4 oc; patch per ic amortized over oc
// ---------------------------------------------------------------------------
__global__ __launch_bounds__(256) void k2_conv_pool(
    const float* __restrict__ in, const float* __restrict__ w2,
    const float* __restrict__ b2, float* __restrict__ out)
{
    unsigned gid = blockIdx.x * 256u + threadIdx.x;
    int pix = gid & 4095;           // 64*64
    int x = pix & 63;
    int y = pix >> 6;
    int tb = blockIdx.x >> 4;       // uniform

    float acc[4][2][2];
    #pragma unroll
    for (int oc = 0; oc < 4; ++oc) {
        float bias = b2[oc];
        #pragma unroll
        for (int pp = 0; pp < 2; ++pp)
        #pragma unroll
        for (int q = 0; q < 2; ++q)
            acc[oc][pp][q] = bias;
    }

    int iy0 = 2 * y - 2, ix0 = 2 * x - 2;

    for (int ic = 0; ic < 4; ++ic) {
        const float* base = in + (((size_t)tb * 4 + ic) << 14);
        float p[6][6];
        #pragma unroll
        for (int r = 0; r < 6; ++r) {
            int iy = iy0 + r;
            bool yok = (unsigned)iy < 128u;
            #pragma unroll
            for (int c = 0; c < 6; ++c) {
                int ix = ix0 + c;
                p[r][c] = (yok && (unsigned)ix < 128u) ? base[(iy << 7) + ix] : 0.f;
            }
        }
        #pragma unroll
        for (int oc = 0; oc < 4; ++oc) {
            const float* w = w2 + (oc * 4 + ic) * 25;   // uniform -> s_load
            #pragma unroll
            for (int pp = 0; pp < 2; ++pp)
            #pragma unroll
            for (int q = 0; q < 2; ++q) {
                #pragma unroll
                for (int ky = 0; ky < 5; ++ky)
                #pragma unroll
                for (int kx = 0; kx < 5; ++kx)
                    acc[oc][pp][q] = fmaf(p[pp + ky][q + kx], w[ky * 5 + kx],
                                          acc[oc][pp][q]);
            }
        }
    }

    #pragma unroll
    for (int oc = 0; oc < 4; ++oc) {
        float m = 0.f;
        #pragma unroll
        for (int pp = 0; pp < 2; ++pp)
        #pragma unroll
        for (int q = 0; q < 2; ++q)
            m = fmaxf(m, acc[oc][pp][q]);
        out[(((size_t)tb * 4 + oc) << 12) + pix] = m;
    }
}

// ---------------------------------------------------------------------------
// k3: conv 4->32 (5x5, same) input-gate precompute
//     in (256,4,64,64) -> out (256,32,64,64)
// thread = pixel; computes ALL 32 output channels (100 loads : 3200 FMA)
// ---------------------------------------------------------------------------
__global__ __launch_bounds__(256) void k3_convx(
    const float* __restrict__ in, const float* __restrict__ wx,
    const float* __restrict__ bx, float* __restrict__ out)
{
    unsigned gid = blockIdx.x * 256u + threadIdx.x;
    int pix = gid & 4095;
    int x = pix & 63;
    int y = pix >> 6;
    int tb = blockIdx.x >> 4;       // uniform

    float acc[32];
    #pragma unroll
    for (int oc = 0; oc < 32; ++oc) acc[oc] = bx[oc];

    for (int ic = 0; ic < 4; ++ic) {
        const float* base = in + (((size_t)tb * 4 + ic) << 12);
        float p[25];
        #pragma unroll
        for (int ky = 0; ky < 5; ++ky) {
            int iy = y + ky - 2;
            bool yok = (unsigned)iy < 64u;
            #pragma unroll
            for (int kx = 0; kx < 5; ++kx) {
                int ix = x + kx - 2;
                p[ky * 5 + kx] =
                    (yok && (unsigned)ix < 64u) ? base[(iy << 6) + ix] : 0.f;
            }
        }
        #pragma unroll
        for (int oc = 0; oc < 32; ++oc) {
            const float* w = wx + (oc * 4 + ic) * 25;   // uniform -> s_load
            #pragma unroll
            for (int k = 0; k < 25; ++k)
                acc[oc] = fmaf(p[k], w[k], acc[oc]);
        }
    }

    #pragma unroll
    for (int oc = 0; oc < 32; ++oc)
        out[(((size_t)tb * 32 + oc) << 12) + pix] = acc[oc];
}

// ---------------------------------------------------------------------------
// k4: one ConvLSTM step.
//     thread = (b, pixel); computes ALL 8 channels x 4 gates (32 accs,
//     200 loads : 6400 FMA)
// ---------------------------------------------------------------------------
__global__ __launch_bounds__(256) void k4_lstm_step(
    const float* __restrict__ xg_t, const float* __restrict__ h_in,
    const float* __restrict__ c_in, const float* __restrict__ wh,
    const float* __restrict__ bh, const float* __restrict__ wci,
    const float* __restrict__ wcf, const float* __restrict__ wco,
    float* __restrict__ h_out, float* __restrict__ c_out)
{
    unsigned gid = blockIdx.x * 256u + threadIdx.x;
    int pix = gid & 4095;
    int x = pix & 63;
    int y = pix >> 6;
    int b = blockIdx.x >> 4;        // uniform

    float acc[32];                   // [gate*8 + ch]
    #pragma unroll
    for (int og = 0; og < 32; ++og)
        acc[og] = bh[og] + xg_t[(((size_t)b * 32 + og) << 12) + pix];

    for (int ic = 0; ic < 8; ++ic) {
        const float* base = h_in + (((size_t)b * 8 + ic) << 12);
        float p[25];
        #pragma unroll
        for (int ky = 0; ky < 5; ++ky) {
            int iy = y + ky - 2;
            bool yok = (unsigned)iy < 64u;
            #pragma unroll
            for (int kx = 0; kx < 5; ++kx) {
                int ix = x + kx - 2;
                p[ky * 5 + kx] =
                    (yok && (unsigned)ix < 64u) ? base[(iy << 6) + ix] : 0.f;
            }
        }
        #pragma unroll
        for (int og = 0; og < 32; ++og) {
            const float* w = wh + (og * 8 + ic) * 25;   // uniform -> s_load
            #pragma unroll
            for (int k = 0; k < 25; ++k)
                acc[og] = fmaf(p[k], w[k], acc[og]);
        }
    }

    #pragma unroll
    for (int ch = 0; ch < 8; ++ch) {
        size_t idx = (((size_t)b * 8 + ch) << 12) + pix;
        int pidx = (ch << 12) + pix;
        float c_old = c_in[idx];
        float i = sigmoidf_(acc[ch] + c_old * wci[pidx]);
        float f = sigmoidf_(acc[8 + ch] + c_old * wcf[pidx]);
        float c_new = f * c_old + i * tanhf(acc[16 + ch]);
        float o = sigmoidf_(acc[24 + ch] + c_new * wco[pidx]);
        h_out[idx] = o * tanhf(c_new);
        c_out[idx] = c_new;
    }
}

// ---------------------------------------------------------------------------
extern "C" void kernel_launch(void* const* d_in, const int* in_sizes, int n_in,
                              void* d_out, int out_size, void* d_ws, size_t ws_size,
                              hipStream_t stream)
{
    const float* obs = (const float*)d_in[0];
    const float* w1  = (const float*)d_in[1];
    const float* b1  = (const float*)d_in[2];
    const float* w2  = (const float*)d_in[3];
    const float* b2  = (const float*)d_in[4];
    const float* wx  = (const float*)d_in[5];
    const float* bx  = (const float*)d_in[6];
    const float* wh  = (const float*)d_in[7];
    const float* bh  = (const float*)d_in[8];
    const float* wci = (const float*)d_in[9];
    const float* wcf = (const float*)d_in[10];
    const float* wco = (const float*)d_in[11];

    float* ws = (float*)d_ws;
    // layout (floats):
    //   [0, 33.5M)        xg (8,32,32,64,64)  -- overlays s1 (dead after k2)
    //   [33.5M, 37.7M)    s2 (256,4,64,64)
    //   [37.7M, ...)      h0, h1, c   (each 1,048,576)
    float* s1 = ws;
    float* xg = ws;
    float* s2 = ws + 33554432;
    float* h0 = ws + 37748736;
    float* h1 = h0 + 1048576;
    float* cc = h1 + 1048576;

    k1_conv_pool<<<16384, 256, 0, stream>>>(obs, w1, b1, s1);
    k2_conv_pool<<<4096, 256, 0, stream>>>(s1, w2, b2, s2);
    k3_convx   <<<4096, 256, 0, stream>>>(s2, wx, bx, xg);

    hipMemsetAsync(h0, 0, (size_t)1048576 * 4, stream);
    hipMemsetAsync(cc, 0, (size_t)1048576 * 4, stream);

    float* hb[2] = {h0, h1};
    for (int t = 0; t < 8; ++t) {
        const float* h_in = hb[t & 1];
        float* h_out = (t == 7) ? (float*)d_out : hb[(t + 1) & 1];
        float* c_out = (t == 7) ? ((float*)d_out + 1048576) : cc;
        k4_lstm_step<<<512, 256, 0, stream>>>(
            xg + (size_t)t * 4194304, h_in, cc, wh, bh, wci, wcf, wco,
            h_out, c_out);
    }
}

// Round 3
// 563.922 us; speedup vs baseline: 2.1828x; 1.1347x over previous
//
#include <hip/hip_runtime.h>
#include <math.h>

#define DEVINL __device__ __forceinline__

DEVINL float sigmoidf_(float x) { return 1.0f / (1.0f + expf(-x)); }

// ---------------------------------------------------------------------------
// kT: one-time weight transpose to tap-major [ic][tap][oc] layouts.
//   w1 (4,1,25)  -> w1T (25,4)
//   w2 (4,4,25)  -> w2T (4,25,4)
//   wx (32,4,25) -> wxT (4,25,32)
//   wh (32,8,25) -> whT (8,25,32)
// ---------------------------------------------------------------------------
__global__ __launch_bounds__(256) void kT_transpose(
    const float* __restrict__ w1, const float* __restrict__ w2,
    const float* __restrict__ wx, const float* __restrict__ wh,
    float* __restrict__ w1T, float* __restrict__ w2T,
    float* __restrict__ wxT, float* __restrict__ whT)
{
    int t = blockIdx.x * 256 + threadIdx.x;
    if (t < 100) {                       // w1: oc*25 + k
        int oc = t / 25, k = t % 25;
        w1T[k * 4 + oc] = w1[t];
    }
    if (t < 400) {                       // w2: (oc*4 + ic)*25 + k
        int oc = t / 100, ic = (t / 25) % 4, k = t % 25;
        w2T[(ic * 25 + k) * 4 + oc] = w2[t];
    }
    if (t < 3200) {                      // wx: (oc*4 + ic)*25 + k
        int oc = t / 100, ic = (t / 25) % 4, k = t % 25;
        wxT[(ic * 25 + k) * 32 + oc] = wx[t];
    }
    if (t < 6400) {                      // wh: (og*8 + ic)*25 + k
        int og = t / 200, ic = (t / 25) % 8, k = t % 25;
        whT[(ic * 25 + k) * 32 + og] = wh[t];
    }
}

// ---------------------------------------------------------------------------
// k1: conv 1->4 + relu + maxpool2, obs (256,1,256,256) -> (256,4,128,128)
// thread = 2 adjacent pooled pixels; all 4 oc; float2 coalesced patch loads
// grid: 256 img * 32 blocks (8192 threads = 128 rows * 64 pairs)
// ---------------------------------------------------------------------------
__global__ __launch_bounds__(256) void k1_conv_pool(
    const float* __restrict__ obs, const float* __restrict__ w1T,
    const float* __restrict__ b1, float* __restrict__ out)
{
    unsigned gid = blockIdx.x * 256u + threadIdx.x;
    int id = gid & 8191;
    int xp = id & 63;            // pixel-pair index
    int y  = id >> 6;
    int x  = xp << 1;            // first pooled pixel
    int tb = blockIdx.x >> 5;    // uniform

    const float* in = obs + ((size_t)tb << 16);
    int iy0 = 2 * y - 2;
    int ix0 = 4 * xp - 2;        // even

    float p[6][8];
    #pragma unroll
    for (int r = 0; r < 6; ++r) {
        int iy = iy0 + r;
        bool yok = (unsigned)iy < 256u;
        #pragma unroll
        for (int c2 = 0; c2 < 4; ++c2) {
            int ix = ix0 + 2 * c2;
            float2 v = make_float2(0.f, 0.f);
            if (yok && (unsigned)ix < 256u)
                v = *(const float2*)(in + (iy << 8) + ix);
            p[r][2 * c2]     = v.x;
            p[r][2 * c2 + 1] = v.y;
        }
    }

    #pragma unroll
    for (int oc = 0; oc < 4; ++oc) {
        float bias = b1[oc];
        float m0 = 0.f, m1 = 0.f;        // relu floor
        #pragma unroll
        for (int pp = 0; pp < 2; ++pp)
        #pragma unroll
        for (int q = 0; q < 2; ++q) {
            float a0 = bias, a1 = bias;
            #pragma unroll
            for (int ky = 0; ky < 5; ++ky)
            #pragma unroll
            for (int kx = 0; kx < 5; ++kx) {
                float w = w1T[(ky * 5 + kx) * 4 + oc];
                a0 = fmaf(p[pp + ky][q + kx],     w, a0);
                a1 = fmaf(p[pp + ky][q + kx + 2], w, a1);
            }
            m0 = fmaxf(m0, a0);
            m1 = fmaxf(m1, a1);
        }
        *(float2*)(out + (((size_t)tb * 4 + oc) << 14) + (y << 7) + x) =
            make_float2(m0, m1);
    }
}

// ---------------------------------------------------------------------------
// k2: conv 4->4 + relu + maxpool2, (256,4,128,128) -> (256,4,64,64)
// thread = 2 adjacent pooled pixels; tap-major w2T
// grid: 256 img * 8 blocks (2048 threads = 64 rows * 32 pairs)
// ---------------------------------------------------------------------------
__global__ __launch_bounds__(256) void k2_conv_pool(
    const float* __restrict__ in, const float* __restrict__ w2T,
    const float* __restrict__ b2, float* __restrict__ out)
{
    unsigned gid = blockIdx.x * 256u + threadIdx.x;
    int id = gid & 2047;
    int xp = id & 31;
    int y  = id >> 5;
    int x  = xp << 1;
    int tb = blockIdx.x >> 3;    // uniform

    float acc[4][2][4];          // [oc][pix][pool-pos]
    #pragma unroll
    for (int oc = 0; oc < 4; ++oc) {
        float bias = b2[oc];
        #pragma unroll
        for (int px = 0; px < 2; ++px)
        #pragma unroll
        for (int pq = 0; pq < 4; ++pq)
            acc[oc][px][pq] = bias;
    }

    int iy0 = 2 * y - 2;
    int ix0 = 4 * xp - 2;

    for (int ic = 0; ic < 4; ++ic) {
        const float* base = in + (((size_t)tb * 4 + ic) << 14);
        float p[6][8];
        #pragma unroll
        for (int r = 0; r < 6; ++r) {
            int iy = iy0 + r;
            bool yok = (unsigned)iy < 128u;
            #pragma unroll
            for (int c2 = 0; c2 < 4; ++c2) {
                int ix = ix0 + 2 * c2;
                float2 v = make_float2(0.f, 0.f);
                if (yok && (unsigned)ix < 128u)
                    v = *(const float2*)(base + (iy << 7) + ix);
                p[r][2 * c2]     = v.x;
                p[r][2 * c2 + 1] = v.y;
            }
        }
        #pragma unroll
        for (int k = 0; k < 25; ++k) {
            int ky = k / 5, kx = k % 5;
            const float* w = w2T + (ic * 25 + k) * 4;   // uniform, 16B aligned
            #pragma unroll
            for (int oc = 0; oc < 4; ++oc) {
                float wv = w[oc];
                #pragma unroll
                for (int pp = 0; pp < 2; ++pp)
                #pragma unroll
                for (int q = 0; q < 2; ++q) {
                    acc[oc][0][pp * 2 + q] =
                        fmaf(p[pp + ky][q + kx], wv, acc[oc][0][pp * 2 + q]);
                    acc[oc][1][pp * 2 + q] =
                        fmaf(p[pp + ky][q + kx + 2], wv, acc[oc][1][pp * 2 + q]);
                }
            }
        }
    }

    #pragma unroll
    for (int oc = 0; oc < 4; ++oc) {
        float m0 = 0.f, m1 = 0.f;
        #pragma unroll
        for (int pq = 0; pq < 4; ++pq) {
            m0 = fmaxf(m0, acc[oc][0][pq]);
            m1 = fmaxf(m1, acc[oc][1][pq]);
        }
        *(float2*)(out + (((size_t)tb * 4 + oc) << 12) + (y << 6) + x) =
            make_float2(m0, m1);
    }
}

// ---------------------------------------------------------------------------
// k3: conv 4->32 gate precompute, (256,4,64,64) -> (256,32,64,64)
// thread = 2 adjacent pixels, all 32 oc; tap-major wxT (dwordx16 x2 per tap)
// grid: 256 img * 8 blocks (2048 threads = 64 rows * 32 pairs)
// ---------------------------------------------------------------------------
__global__ __launch_bounds__(256) void k3_convx(
    const float* __restrict__ in, const float* __restrict__ wxT,
    const float* __restrict__ bx, float* __restrict__ out)
{
    unsigned gid = blockIdx.x * 256u + threadIdx.x;
    int id = gid & 2047;
    int xp = id & 31;
    int y  = id >> 5;
    int x  = xp << 1;
    int tb = blockIdx.x >> 3;    // uniform

    float acc[32][2];
    #pragma unroll
    for (int oc = 0; oc < 32; ++oc) {
        float bias = bx[oc];
        acc[oc][0] = bias;
        acc[oc][1] = bias;
    }

    for (int ic = 0; ic < 4; ++ic) {
        const float* base = in + (((size_t)tb * 4 + ic) << 12);
        float p[5][6];
        #pragma unroll
        for (int r = 0; r < 5; ++r) {
            int iy = y + r - 2;
            bool yok = (unsigned)iy < 64u;
            #pragma unroll
            for (int c2 = 0; c2 < 3; ++c2) {
                int ix = x - 2 + 2 * c2;
                float2 v = make_float2(0.f, 0.f);
                if (yok && (unsigned)ix < 64u)
                    v = *(const float2*)(base + (iy << 6) + ix);
                p[r][2 * c2]     = v.x;
                p[r][2 * c2 + 1] = v.y;
            }
        }
        #pragma unroll
        for (int k = 0; k < 25; ++k) {
            int ky = k / 5, kx = k % 5;
            const float* w = wxT + (ic * 25 + k) * 32;  // uniform, 64B aligned
            float v0 = p[ky][kx];
            float v1 = p[ky][kx + 1];
            #pragma unroll
            for (int oc = 0; oc < 32; ++oc) {
                float wv = w[oc];
                acc[oc][0] = fmaf(v0, wv, acc[oc][0]);
                acc[oc][1] = fmaf(v1, wv, acc[oc][1]);
            }
        }
    }

    #pragma unroll
    for (int oc = 0; oc < 32; ++oc)
        *(float2*)(out + (((size_t)tb * 32 + oc) << 12) + (y << 6) + x) =
            make_float2(acc[oc][0], acc[oc][1]);
}

// ---------------------------------------------------------------------------
// k4: one ConvLSTM step, thread = (b, pixel), all 8 ch x 4 gates
// tap-major whT (dwordx16 x2 per tap)
// ---------------------------------------------------------------------------
__global__ __launch_bounds__(256) void k4_lstm_step(
    const float* __restrict__ xg_t, const float* __restrict__ h_in,
    const float* __restrict__ c_in, const float* __restrict__ whT,
    const float* __restrict__ bh, const float* __restrict__ wci,
    const float* __restrict__ wcf, const float* __restrict__ wco,
    float* __restrict__ h_out, float* __restrict__ c_out)
{
    unsigned gid = blockIdx.x * 256u + threadIdx.x;
    int pix = gid & 4095;
    int x = pix & 63;
    int y = pix >> 6;
    int b = blockIdx.x >> 4;     // uniform

    float acc[32];               // [gate*8 + ch]
    #pragma unroll
    for (int og = 0; og < 32; ++og)
        acc[og] = bh[og] + xg_t[(((size_t)b * 32 + og) << 12) + pix];

    for (int ic = 0; ic < 8; ++ic) {
        const float* base = h_in + (((size_t)b * 8 + ic) << 12);
        float p[25];
        #pragma unroll
        for (int ky = 0; ky < 5; ++ky) {
            int iy = y + ky - 2;
            bool yok = (unsigned)iy < 64u;
            #pragma unroll
            for (int kx = 0; kx < 5; ++kx) {
                int ix = x + kx - 2;
                p[ky * 5 + kx] =
                    (yok && (unsigned)ix < 64u) ? base[(iy << 6) + ix] : 0.f;
            }
        }
        #pragma unroll
        for (int k = 0; k < 25; ++k) {
            const float* w = whT + (ic * 25 + k) * 32;  // uniform, 64B aligned
            float v = p[k];
            #pragma unroll
            for (int og = 0; og < 32; ++og)
                acc[og] = fmaf(v, w[og], acc[og]);
        }
    }

    #pragma unroll
    for (int ch = 0; ch < 8; ++ch) {
        size_t idx = (((size_t)b * 8 + ch) << 12) + pix;
        int pidx = (ch << 12) + pix;
        float c_old = c_in[idx];
        float i = sigmoidf_(acc[ch] + c_old * wci[pidx]);
        float f = sigmoidf_(acc[8 + ch] + c_old * wcf[pidx]);
        float c_new = f * c_old + i * tanhf(acc[16 + ch]);
        float o = sigmoidf_(acc[24 + ch] + c_new * wco[pidx]);
        h_out[idx] = o * tanhf(c_new);
        c_out[idx] = c_new;
    }
}

// ---------------------------------------------------------------------------
extern "C" void kernel_launch(void* const* d_in, const int* in_sizes, int n_in,
                              void* d_out, int out_size, void* d_ws, size_t ws_size,
                              hipStream_t stream)
{
    const float* obs = (const float*)d_in[0];
    const float* w1  = (const float*)d_in[1];
    const float* b1  = (const float*)d_in[2];
    const float* w2  = (const float*)d_in[3];
    const float* b2  = (const float*)d_in[4];
    const float* wx  = (const float*)d_in[5];
    const float* bx  = (const float*)d_in[6];
    const float* wh  = (const float*)d_in[7];
    const float* bh  = (const float*)d_in[8];
    const float* wci = (const float*)d_in[9];
    const float* wcf = (const float*)d_in[10];
    const float* wco = (const float*)d_in[11];

    float* ws = (float*)d_ws;
    // layout (floats):
    //   [0, 33.5M)        xg (8,32,32,64,64)  -- overlays s1 (dead after k2)
    //   [33.5M, 37.7M)    s2 (256,4,64,64)
    //   [37.7M, +3M)      h0, h1, c (1,048,576 each)
    //   [40,894,464, +10,240)  w1T(128) w2T(512) wxT(3200) whT(6400)
    float* s1 = ws;
    float* xg = ws;
    float* s2 = ws + 33554432;
    float* h0 = ws + 37748736;
    float* h1 = h0 + 1048576;
    float* cc = h1 + 1048576;
    float* w1T = ws + 40894464;
    float* w2T = w1T + 128;
    float* wxT = w1T + 640;
    float* whT = w1T + 3840;

    kT_transpose<<<25, 256, 0, stream>>>(w1, w2, wx, wh, w1T, w2T, wxT, whT);

    k1_conv_pool<<<8192, 256, 0, stream>>>(obs, w1T, b1, s1);
    k2_conv_pool<<<2048, 256, 0, stream>>>(s1, w2T, b2, s2);
    k3_convx   <<<2048, 256, 0, stream>>>(s2, wxT, bx, xg);

    hipMemsetAsync(h0, 0, (size_t)1048576 * 4, stream);
    hipMemsetAsync(cc, 0, (size_t)1048576 * 4, stream);

    float* hb[2] = {h0, h1};
    for (int t = 0; t < 8; ++t) {
        const float* h_in = hb[t & 1];
        float* h_out = (t == 7) ? (float*)d_out : hb[(t + 1) & 1];
        float* c_out = (t == 7) ? ((float*)d_out + 1048576) : cc;
        k4_lstm_step<<<512, 256, 0, stream>>>(
            xg + (size_t)t * 4194304, h_in, cc, whT, bh, wci, wcf, wco,
            h_out, c_out);
    }
}

// Round 4
// 238.186 us; speedup vs baseline: 5.1679x; 2.3676x over previous
//
#include <hip/hip_runtime.h>
#include <math.h>

typedef _Float16 f16x8 __attribute__((ext_vector_type(8)));
typedef float    f32x16 __attribute__((ext_vector_type(16)));

#define DEVINL __device__ __forceinline__

DEVINL float fast_sigmoid(float x) {
    x = fminf(fmaxf(x, -30.f), 30.f);
    return 1.0f / (1.0f + __expf(-x));
}
DEVINL float fast_tanh(float x) {
    x = fminf(fmaxf(x, -15.f), 15.f);
    float e = __expf(-2.f * x);
    return (1.f - e) / (1.f + e);
}
DEVINL f16x8 f16x8_zero() {
    f16x8 v;
    #pragma unroll
    for (int j = 0; j < 8; ++j) v[j] = (_Float16)0.f;
    return v;
}

// tap enumeration: t<25: ky=t/5, kx=t%5 ; t in {25,26,27}: zero-weight pad
// (points at center tap so the LDS address stays valid)
#define TKY(t) ((t) < 25 ? (t) / 5 : 2)
#define TKX(t) ((t) < 25 ? (t) % 5 : 2)

// ---------------------------------------------------------------------------
// kT_prep: weight repack (one tiny launch).
//  w1T (25,4), w2T (4,25,4): tap-major for VALU convs.
//  whF/wxF [14 chunks][64 lanes][8] f16: per-lane MFMA A-fragments.
//    lane l -> og' = l&31 (og' = ch*4+gate -> og = gate*8+ch), K-group g=l>>5
//    chunk q, elem j -> tap = 2q+g, ic = j
//  btot[og'] = bx[og]+bh[og]   (both biases folded into k3's xg output)
// ---------------------------------------------------------------------------
__global__ void kT_prep(const float* __restrict__ w1, const float* __restrict__ w2,
                        const float* __restrict__ wx, const float* __restrict__ wh,
                        const float* __restrict__ bx, const float* __restrict__ bh,
                        float* __restrict__ w1T, float* __restrict__ w2T,
                        _Float16* __restrict__ wxF, _Float16* __restrict__ whF,
                        float* __restrict__ btot)
{
    int t = threadIdx.x;
    for (int i = t; i < 100; i += 256) {
        int oc = i / 25, k = i % 25;
        w1T[k * 4 + oc] = w1[i];
    }
    for (int i = t; i < 400; i += 256) {
        int oc = i / 100, ic = (i / 25) % 4, k = i % 25;
        w2T[(ic * 25 + k) * 4 + oc] = w2[i];
    }
    for (int i = t; i < 14 * 64 * 8; i += 256) {
        int j = i & 7, l = (i >> 3) & 63, q = i >> 9;
        int gate = l & 3, ch = (l & 31) >> 2, g = l >> 5;
        int og = gate * 8 + ch;
        int tap = 2 * q + g;
        float vh = (tap < 25) ? wh[(og * 8 + j) * 25 + tap] : 0.f;
        float vx = (tap < 25 && j < 4) ? wx[(og * 4 + j) * 25 + tap] : 0.f;
        whF[i] = (_Float16)vh;
        wxF[i] = (_Float16)vx;
    }
    if (t < 32) {
        int og = (t & 3) * 8 + (t >> 2);
        btot[t] = bx[og] + bh[og];
    }
}

// ---------------------------------------------------------------------------
// k1: conv 1->4 + relu + maxpool2 (VALU), obs (256,1,256,256)->(256,4,128,128)
// ---------------------------------------------------------------------------
__global__ __launch_bounds__(256) void k1_conv_pool(
    const float* __restrict__ obs, const float* __restrict__ w1T,
    const float* __restrict__ b1, float* __restrict__ out)
{
    unsigned gid = blockIdx.x * 256u + threadIdx.x;
    int id = gid & 8191;
    int xp = id & 63;
    int y  = id >> 6;
    int x  = xp << 1;
    int tb = blockIdx.x >> 5;

    const float* in = obs + ((size_t)tb << 16);
    int iy0 = 2 * y - 2;
    int ix0 = 4 * xp - 2;

    float p[6][8];
    #pragma unroll
    for (int r = 0; r < 6; ++r) {
        int iy = iy0 + r;
        bool yok = (unsigned)iy < 256u;
        #pragma unroll
        for (int c2 = 0; c2 < 4; ++c2) {
            int ix = ix0 + 2 * c2;
            float2 v = make_float2(0.f, 0.f);
            if (yok && (unsigned)ix < 256u)
                v = *(const float2*)(in + (iy << 8) + ix);
            p[r][2 * c2]     = v.x;
            p[r][2 * c2 + 1] = v.y;
        }
    }

    #pragma unroll
    for (int oc = 0; oc < 4; ++oc) {
        float bias = b1[oc];
        float m0 = 0.f, m1 = 0.f;
        #pragma unroll
        for (int pp = 0; pp < 2; ++pp)
        #pragma unroll
        for (int q = 0; q < 2; ++q) {
            float a0 = bias, a1 = bias;
            #pragma unroll
            for (int ky = 0; ky < 5; ++ky)
            #pragma unroll
            for (int kx = 0; kx < 5; ++kx) {
                float w = w1T[(ky * 5 + kx) * 4 + oc];
                a0 = fmaf(p[pp + ky][q + kx],     w, a0);
                a1 = fmaf(p[pp + ky][q + kx + 2], w, a1);
            }
            m0 = fmaxf(m0, a0);
            m1 = fmaxf(m1, a1);
        }
        *(float2*)(out + (((size_t)tb * 4 + oc) << 14) + (y << 7) + x) =
            make_float2(m0, m1);
    }
}

// ---------------------------------------------------------------------------
// k2: conv 4->4 + relu + maxpool2 (VALU), (256,4,128,128) -> s2cl channel-last
//     f16 [f][4096 px][8] (ic 0..3 data, 4..7 zero) for MFMA staging.
// ---------------------------------------------------------------------------
__global__ __launch_bounds__(256) void k2_conv_pool(
    const float* __restrict__ in, const float* __restrict__ w2T,
    const float* __restrict__ b2, _Float16* __restrict__ s2cl)
{
    unsigned gid = blockIdx.x * 256u + threadIdx.x;
    int id = gid & 2047;
    int xp = id & 31;
    int y  = id >> 5;
    int x  = xp << 1;
    int tb = blockIdx.x >> 3;

    float acc[4][2][4];
    #pragma unroll
    for (int oc = 0; oc < 4; ++oc) {
        float bias = b2[oc];
        #pragma unroll
        for (int px = 0; px < 2; ++px)
        #pragma unroll
        for (int pq = 0; pq < 4; ++pq)
            acc[oc][px][pq] = bias;
    }

    int iy0 = 2 * y - 2;
    int ix0 = 4 * xp - 2;

    for (int ic = 0; ic < 4; ++ic) {
        const float* base = in + (((size_t)tb * 4 + ic) << 14);
        float p[6][8];
        #pragma unroll
        for (int r = 0; r < 6; ++r) {
            int iy = iy0 + r;
            bool yok = (unsigned)iy < 128u;
            #pragma unroll
            for (int c2 = 0; c2 < 4; ++c2) {
                int ix = ix0 + 2 * c2;
                float2 v = make_float2(0.f, 0.f);
                if (yok && (unsigned)ix < 128u)
                    v = *(const float2*)(base + (iy << 7) + ix);
                p[r][2 * c2]     = v.x;
                p[r][2 * c2 + 1] = v.y;
            }
        }
        #pragma unroll
        for (int k = 0; k < 25; ++k) {
            int ky = k / 5, kx = k % 5;
            const float* w = w2T + (ic * 25 + k) * 4;
            #pragma unroll
            for (int oc = 0; oc < 4; ++oc) {
                float wv = w[oc];
                #pragma unroll
                for (int pp = 0; pp < 2; ++pp)
                #pragma unroll
                for (int q = 0; q < 2; ++q) {
                    acc[oc][0][pp * 2 + q] =
                        fmaf(p[pp + ky][q + kx], wv, acc[oc][0][pp * 2 + q]);
                    acc[oc][1][pp * 2 + q] =
                        fmaf(p[pp + ky][q + kx + 2], wv, acc[oc][1][pp * 2 + q]);
                }
            }
        }
    }

    f16x8 v0 = f16x8_zero(), v1 = f16x8_zero();
    #pragma unroll
    for (int oc = 0; oc < 4; ++oc) {
        float m0 = 0.f, m1 = 0.f;
        #pragma unroll
        for (int pq = 0; pq < 4; ++pq) {
            m0 = fmaxf(m0, acc[oc][0][pq]);
            m1 = fmaxf(m1, acc[oc][1][pq]);
        }
        v0[oc] = (_Float16)m0;
        v1[oc] = (_Float16)m1;
    }
    _Float16* dst = s2cl + (((size_t)tb << 12) + (y << 6) + x) * 8;
    *(f16x8*)dst       = v0;
    *(f16x8*)(dst + 8) = v1;
}

// ---------------------------------------------------------------------------
// k3: conv 4->32 gate precompute, MFMA implicit GEMM.
//     block = (frame f, 8 rows); LDS tile 12x68 px channel-last f16.
//     xg stored PRE-BIASED in C-fragment layout:
//     xg[f][tile(=y*2+hx)][r4][lane][4] f32
// ---------------------------------------------------------------------------
__global__ __launch_bounds__(256) void k3_mfma(
    const _Float16* __restrict__ s2cl, const _Float16* __restrict__ wxF,
    const float* __restrict__ btot, float* __restrict__ xg)
{
    __shared__ _Float16 lds[12 * 68 * 8];
    int tid = threadIdx.x;
    int lane = tid & 63, w = tid >> 6, g = lane >> 5;
    int f  = blockIdx.x >> 3;
    int y0 = (blockIdx.x & 7) << 3;

    // A-fragments (weights) - held in VGPRs for the whole kernel
    f16x8 wf[14];
    #pragma unroll
    for (int q = 0; q < 14; ++q)
        wf[q] = *(const f16x8*)(wxF + ((size_t)q * 64 + lane) * 8);

    // per-reg bias (row = (r&3)+8*(r>>2)+4*g)
    float bsel[16];
    #pragma unroll
    for (int r = 0; r < 16; ++r) {
        int row0 = (r & 3) + 8 * (r >> 2);
        bsel[r] = g ? btot[row0 + 4] : btot[row0];
    }

    // stage 12 rows (y0-2 .. y0+9), cols -2..65 ; 3 rows per wave
    #pragma unroll
    for (int ii = 0; ii < 3; ++ii) {
        int ly = 3 * w + ii;
        int gy = y0 - 2 + ly;
        f16x8 v = f16x8_zero();
        if ((unsigned)gy < 64u)
            v = *(const f16x8*)(s2cl + (((size_t)f << 12) + (gy << 6) + lane) * 8);
        *(f16x8*)&lds[(ly * 68 + 2 + lane) * 8] = v;
    }
    if (tid < 48) {   // zero halo columns {-2,-1,64,65}
        int r = tid >> 2, cs = tid & 3;
        int col = (cs & 2) ? (66 + (cs & 1)) : (cs & 1);
        *(f16x8*)&lds[(r * 68 + col) * 8] = f16x8_zero();
    }
    __syncthreads();

    // per-lane tap byte-offsets (chunk q covers taps 2q+g)
    int toffs[14];
    #pragma unroll
    for (int q = 0; q < 14; ++q) {
        int o0 = ((TKY(2 * q) - 2) * 68 + (TKX(2 * q) - 2)) * 16;
        int o1 = ((TKY(2 * q + 1) - 2) * 68 + (TKX(2 * q + 1) - 2)) * 16;
        toffs[q] = g ? o1 : o0;
    }

    #pragma unroll
    for (int i = 0; i < 4; ++i) {
        int tt = w * 4 + i;          // 16 tiles per block
        int ry = tt >> 1, hx = tt & 1;
        int tbase = ((ry + 2) * 68 + hx * 32 + (lane & 31) + 2) * 16;

        f32x16 acc;
        #pragma unroll
        for (int r = 0; r < 16; ++r) acc[r] = 0.f;

        #pragma unroll
        for (int q = 0; q < 14; ++q) {
            f16x8 bv = *(const f16x8*)((const char*)lds + tbase + toffs[q]);
            acc = __builtin_amdgcn_mfma_f32_32x32x16_f16(wf[q], bv, acc, 0, 0, 0);
        }

        size_t tl = (size_t)f * 128 + (y0 + ry) * 2 + hx;
        float* dst = xg + tl * 1024 + lane * 4;
        #pragma unroll
        for (int r4 = 0; r4 < 4; ++r4) {
            float4 o = make_float4(acc[4 * r4 + 0] + bsel[4 * r4 + 0],
                                   acc[4 * r4 + 1] + bsel[4 * r4 + 1],
                                   acc[4 * r4 + 2] + bsel[4 * r4 + 2],
                                   acc[4 * r4 + 3] + bsel[4 * r4 + 3]);
            *(float4*)(dst + r4 * 256) = o;
        }
    }
}

// ---------------------------------------------------------------------------
// k4: one ConvLSTM step, MFMA implicit GEMM + in-lane LSTM epilogue.
//     block = (b, 4 rows); LDS tile 8x68 px channel-last f16 of h_prev.
//     lane l, reg r: pixel = hx*32+(l&31), gate = r&3, ch = 2*(r>>2)+(l>>5)
// ---------------------------------------------------------------------------
__global__ __launch_bounds__(256) void k4_mfma(
    const float* __restrict__ xg_t, const _Float16* __restrict__ hprev,
    const _Float16* __restrict__ whF, float* __restrict__ cbuf,
    const float* __restrict__ wci, const float* __restrict__ wcf,
    const float* __restrict__ wco, _Float16* __restrict__ hnext,
    float* __restrict__ out_hc, int last)
{
    __shared__ _Float16 lds[8 * 68 * 8];
    int tid = threadIdx.x;
    int lane = tid & 63, w = tid >> 6, g = lane >> 5;
    int b  = blockIdx.x >> 4;
    int y0 = (blockIdx.x & 15) << 2;

    f16x8 wf[14];
    #pragma unroll
    for (int q = 0; q < 14; ++q)
        wf[q] = *(const f16x8*)(whF + ((size_t)q * 64 + lane) * 8);

    // stage 8 rows (y0-2 .. y0+5); 2 rows per wave
    #pragma unroll
    for (int ii = 0; ii < 2; ++ii) {
        int ly = 2 * w + ii;
        int gy = y0 - 2 + ly;
        f16x8 v = f16x8_zero();
        if ((unsigned)gy < 64u)
            v = *(const f16x8*)(hprev + (((size_t)b << 12) + (gy << 6) + lane) * 8);
        *(f16x8*)&lds[(ly * 68 + 2 + lane) * 8] = v;
    }
    if (tid < 32) {
        int r = tid >> 2, cs = tid & 3;
        int col = (cs & 2) ? (66 + (cs & 1)) : (cs & 1);
        *(f16x8*)&lds[(r * 68 + col) * 8] = f16x8_zero();
    }
    __syncthreads();

    int toffs[14];
    #pragma unroll
    for (int q = 0; q < 14; ++q) {
        int o0 = ((TKY(2 * q) - 2) * 68 + (TKX(2 * q) - 2)) * 16;
        int o1 = ((TKY(2 * q + 1) - 2) * 68 + (TKX(2 * q + 1) - 2)) * 16;
        toffs[q] = g ? o1 : o0;
    }

    #pragma unroll
    for (int i = 0; i < 2; ++i) {
        int tt = w * 2 + i;          // 8 tiles per block
        int ry = tt >> 1, hx = tt & 1;
        size_t tl = (size_t)b * 128 + (y0 + ry) * 2 + hx;

        // accumulator init = xg fragment (pre-biased by k3)
        const float* xsrc = xg_t + tl * 1024 + lane * 4;
        f32x16 acc;
        #pragma unroll
        for (int r4 = 0; r4 < 4; ++r4) {
            float4 v = *(const float4*)(xsrc + r4 * 256);
            acc[4 * r4 + 0] = v.x; acc[4 * r4 + 1] = v.y;
            acc[4 * r4 + 2] = v.z; acc[4 * r4 + 3] = v.w;
        }

        int tbase = ((ry + 2) * 68 + hx * 32 + (lane & 31) + 2) * 16;
        #pragma unroll
        for (int q = 0; q < 14; ++q) {
            f16x8 bv = *(const f16x8*)((const char*)lds + tbase + toffs[q]);
            acc = __builtin_amdgcn_mfma_f32_32x32x16_f16(wf[q], bv, acc, 0, 0, 0);
        }

        int px  = hx * 32 + (lane & 31);
        int pix = (y0 + ry) * 64 + px;
        #pragma unroll
        for (int cc = 0; cc < 4; ++cc) {
            int ch = 2 * cc + g;
            size_t sidx = (((size_t)b * 8 + ch) << 12) + pix;
            int ppix = (ch << 12) + pix;
            float c_old = cbuf[sidx];
            float i_ = fast_sigmoid(acc[4 * cc + 0] + c_old * wci[ppix]);
            float f_ = fast_sigmoid(acc[4 * cc + 1] + c_old * wcf[ppix]);
            float cn = f_ * c_old + i_ * fast_tanh(acc[4 * cc + 2]);
            float o_ = fast_sigmoid(acc[4 * cc + 3] + cn * wco[ppix]);
            float hn = o_ * fast_tanh(cn);
            if (last) {
                out_hc[sidx] = hn;
                out_hc[sidx + 1048576] = cn;
            } else {
                cbuf[sidx] = cn;
                hnext[((((size_t)b << 12) + pix) << 3) + ch] = (_Float16)hn;
            }
        }
    }
}

// ---------------------------------------------------------------------------
extern "C" void kernel_launch(void* const* d_in, const int* in_sizes, int n_in,
                              void* d_out, int out_size, void* d_ws, size_t ws_size,
                              hipStream_t stream)
{
    const float* obs = (const float*)d_in[0];
    const float* w1  = (const float*)d_in[1];
    const float* b1  = (const float*)d_in[2];
    const float* w2  = (const float*)d_in[3];
    const float* b2  = (const float*)d_in[4];
    const float* wx  = (const float*)d_in[5];
    const float* bx  = (const float*)d_in[6];
    const float* wh  = (const float*)d_in[7];
    const float* bh  = (const float*)d_in[8];
    const float* wci = (const float*)d_in[9];
    const float* wcf = (const float*)d_in[10];
    const float* wco = (const float*)d_in[11];

    char* wsb = (char*)d_ws;
    // byte layout:
    //   [0, 134,217,728)            xg f32 (overlays s1, dead after k2)
    //   [134,217,728, 150,994,944)  s2cl f16 [256][4096][8]
    //   [150,994,944, 153,092,096)  hA f16 [32][4096][8]
    //   [153,092,096, 155,189,248)  hB f16
    //   [155,189,248, 159,383,552)  c   f32 [32][8][4096]
    //   [159,383,552, ...)          whF, wxF, btot, w1T, w2T
    float*     s1   = (float*)wsb;
    float*     xg   = (float*)wsb;
    _Float16*  s2cl = (_Float16*)(wsb + 134217728);
    _Float16*  hA   = (_Float16*)(wsb + 150994944);
    _Float16*  hB   = (_Float16*)(wsb + 153092096);
    float*     cbuf = (float*)(wsb + 155189248);
    _Float16*  whF  = (_Float16*)(wsb + 159383552);
    _Float16*  wxF  = (_Float16*)(wsb + 159397888);
    float*     btot = (float*)(wsb + 159412224);
    float*     w1T  = (float*)(wsb + 159412352);
    float*     w2T  = (float*)(wsb + 159412864);

    kT_prep<<<1, 256, 0, stream>>>(w1, w2, wx, wh, bx, bh,
                                   w1T, w2T, wxF, whF, btot);

    k1_conv_pool<<<8192, 256, 0, stream>>>(obs, w1T, b1, s1);
    k2_conv_pool<<<2048, 256, 0, stream>>>(s1, w2T, b2, s2cl);
    k3_mfma     <<<2048, 256, 0, stream>>>(s2cl, wxF, btot, xg);

    hipMemsetAsync(hA,   0, 2097152, stream);
    hipMemsetAsync(cbuf, 0, 4194304, stream);

    for (int t = 0; t < 8; ++t) {
        const _Float16* hp = (t & 1) ? hB : hA;
        _Float16*       hn = (t & 1) ? hA : hB;
        k4_mfma<<<512, 256, 0, stream>>>(
            xg + (size_t)t * 4194304, hp, whF, cbuf,
            wci, wcf, wco, hn, (float*)d_out, t == 7);
    }
}

// Round 5
// 199.431 us; speedup vs baseline: 6.1722x; 1.1943x over previous
//
#include <hip/hip_runtime.h>
#include <math.h>

typedef _Float16 f16x8 __attribute__((ext_vector_type(8)));
typedef float    f32x16 __attribute__((ext_vector_type(16)));

#define DEVINL __device__ __forceinline__

DEVINL float fast_sigmoid(float x) {
    x = fminf(fmaxf(x, -30.f), 30.f);
    return 1.0f / (1.0f + __expf(-x));
}
DEVINL float fast_tanh(float x) {
    x = fminf(fmaxf(x, -15.f), 15.f);
    float e = __expf(-2.f * x);
    return (1.f - e) / (1.f + e);
}
DEVINL f16x8 f16x8_zero() {
    f16x8 v;
    #pragma unroll
    for (int j = 0; j < 8; ++j) v[j] = (_Float16)0.f;
    return v;
}

// tap enumeration for k4 (tap-pair scheme): t<25 real, 25..27 pad (zero wgt)
#define TKY(t) ((t) < 25 ? (t) / 5 : 2)
#define TKX(t) ((t) < 25 ? (t) % 5 : 2)

// ---------------------------------------------------------------------------
// kT_prep: weight repack.
//  w1T (25,4) tap-major for k1 VALU conv.
//  w2F [12][64][8] f16: k2 MFMA A-frags. M row m = oc*4 + qy*2 + qx (m<16),
//    K = (pr<6, pc<8, ic<4): A[m][k] = w2[oc][ic][pr-qy][pc-qx] (valid 5x5).
//  wxF [10][64][8] f16: k3 A-frags. m = gate + ch*4 -> og = gate*8+ch,
//    K = (pr<5, pc<8, ic<4): wx[og][ic][pr][pc] for pc<5.
//  whF [14][64][8] f16: k4 A-frags, tap-pair scheme (chunk q: taps 2q+g).
//  btot[m] = bx[og] + bh[og].
// ---------------------------------------------------------------------------
__global__ void kT_prep(const float* __restrict__ w1, const float* __restrict__ w2,
                        const float* __restrict__ wx, const float* __restrict__ wh,
                        const float* __restrict__ bx, const float* __restrict__ bh,
                        float* __restrict__ w1T, _Float16* __restrict__ w2F,
                        _Float16* __restrict__ wxF, _Float16* __restrict__ whF,
                        float* __restrict__ btot)
{
    int t = blockIdx.x * 256 + threadIdx.x;
    int stride = gridDim.x * 256;
    for (int i = t; i < 100; i += stride) {
        int oc = i / 25, k = i % 25;
        w1T[k * 4 + oc] = w1[i];
    }
    for (int i = t; i < 12 * 512; i += stride) {      // w2F
        int j = i & 7, l = (i >> 3) & 63, q = i >> 9;
        int g = l >> 5, m = l & 31;
        int k = q * 16 + g * 8 + j;
        int pr = k >> 5, pc = (k >> 2) & 7, ic = k & 3;
        float v = 0.f;
        if (m < 16) {
            int oc = m >> 2, qy = (m >> 1) & 1, qx = m & 1;
            int ky = pr - qy, kx = pc - qx;
            if ((unsigned)ky < 5u && (unsigned)kx < 5u)
                v = w2[(oc * 4 + ic) * 25 + ky * 5 + kx];
        }
        w2F[i] = (_Float16)v;
    }
    for (int i = t; i < 10 * 512; i += stride) {      // wxF
        int j = i & 7, l = (i >> 3) & 63, q = i >> 9;
        int g = l >> 5, m = l & 31;
        int k = q * 16 + g * 8 + j;
        int pr = k >> 5, pc = (k >> 2) & 7, ic = k & 3;
        int og = (m & 3) * 8 + (m >> 2);
        float v = (pr < 5 && pc < 5) ? wx[(og * 4 + ic) * 25 + pr * 5 + pc] : 0.f;
        wxF[i] = (_Float16)v;
    }
    for (int i = t; i < 14 * 512; i += stride) {      // whF
        int j = i & 7, l = (i >> 3) & 63, q = i >> 9;
        int g = l >> 5, m = l & 31;
        int og = (m & 3) * 8 + (m >> 2);
        int tap = 2 * q + g;
        float v = (tap < 25) ? wh[(og * 8 + j) * 25 + tap] : 0.f;
        whF[i] = (_Float16)v;
    }
    if (t < 32) {
        int og = (t & 3) * 8 + (t >> 2);
        btot[t] = bx[og] + bh[og];
    }
}

// ---------------------------------------------------------------------------
// k1: conv 1->4 + relu + maxpool2 (VALU, LDS-staged).
//     obs (256,1,256,256) f32 -> s1cl [img][128*128 px][4ch] f16.
// block: 1 img x 4 pooled rows x 128 pooled cols. thread = 2 adjacent px.
// ---------------------------------------------------------------------------
__global__ __launch_bounds__(256) void k1_conv_pool(
    const float* __restrict__ obs, const float* __restrict__ w1T,
    const float* __restrict__ b1, _Float16* __restrict__ s1cl)
{
    __shared__ float lds[12 * 260];          // rows 8yt-2..+9, cols -2..257
    int tid = threadIdx.x;
    int yt = blockIdx.x & 31;
    int tb = blockIdx.x >> 5;

    const float* in = obs + ((size_t)tb << 16);
    // stage 12 x 130 float2
    for (int i = tid; i < 12 * 130; i += 256) {
        int r = i / 130, c2 = i % 130;
        int gy = (yt << 3) - 2 + r;
        int gx = 2 * c2 - 2;
        float2 v = make_float2(0.f, 0.f);
        if ((unsigned)gy < 256u && (unsigned)gx < 255u)
            v = *(const float2*)(in + (gy << 8) + gx);
        lds[r * 260 + 2 * c2]     = v.x;
        lds[r * 260 + 2 * c2 + 1] = v.y;
    }
    __syncthreads();

    int ly  = tid >> 6;          // 0..3
    int px0 = 2 * (tid & 63);    // 0..126
    int r0 = 2 * ly;
    int c0 = 2 * px0;            // multiple of 4 -> 16B aligned

    float p[6][8];
    #pragma unroll
    for (int r = 0; r < 6; ++r) {
        #pragma unroll
        for (int c4 = 0; c4 < 2; ++c4) {
            float4 v = *(const float4*)&lds[(r0 + r) * 260 + c0 + 4 * c4];
            p[r][4 * c4 + 0] = v.x; p[r][4 * c4 + 1] = v.y;
            p[r][4 * c4 + 2] = v.z; p[r][4 * c4 + 3] = v.w;
        }
    }

    f16x8 outv;
    #pragma unroll
    for (int oc = 0; oc < 4; ++oc) {
        float bias = b1[oc];
        float m0 = 0.f, m1 = 0.f;            // relu floor
        #pragma unroll
        for (int pp = 0; pp < 2; ++pp)
        #pragma unroll
        for (int q = 0; q < 2; ++q) {
            float a0 = bias, a1 = bias;
            #pragma unroll
            for (int ky = 0; ky < 5; ++ky)
            #pragma unroll
            for (int kx = 0; kx < 5; ++kx) {
                float w = w1T[(ky * 5 + kx) * 4 + oc];
                a0 = fmaf(p[pp + ky][q + kx],     w, a0);
                a1 = fmaf(p[pp + ky][q + kx + 2], w, a1);
            }
            m0 = fmaxf(m0, a0);
            m1 = fmaxf(m1, a1);
        }
        outv[oc]     = (_Float16)m0;
        outv[oc + 4] = (_Float16)m1;
    }
    int gyp = (yt << 2) + ly;
    *(f16x8*)(s1cl + ((((size_t)tb << 14) + (gyp << 7) + px0) << 2)) = outv;
}

// ---------------------------------------------------------------------------
// k2: conv 4->4 + relu + maxpool2 as MFMA (pool folded into M).
//     s1cl [img][16384][4] f16 -> s2cl [img][4096][4] f16.
// block: 1 img x 8 pooled rows. LDS: 20 rows x 136 cols x 4ch f16.
// ---------------------------------------------------------------------------
__global__ __launch_bounds__(256) void k2_mfma(
    const _Float16* __restrict__ s1cl, const _Float16* __restrict__ w2F,
    const float* __restrict__ b2, _Float16* __restrict__ s2cl)
{
    __shared__ _Float16 lds[20 * 136 * 4];   // pitch 1088 B/row
    int tid = threadIdx.x;
    int lane = tid & 63, w = tid >> 6, g = lane >> 5;
    int f  = blockIdx.x >> 3;
    int yt = blockIdx.x & 7;
    int y0 = yt << 3;

    f16x8 wf[12];
    #pragma unroll
    for (int q = 0; q < 12; ++q)
        wf[q] = *(const f16x8*)(w2F + ((size_t)q * 64 + lane) * 8);

    float bA = b2[g], bB = b2[g + 2];

    for (int i = tid; i < 20 * 68; i += 256) {
        int r = i / 68, u = i % 68;
        int gy = (yt << 4) - 2 + r;
        int gx = 2 * u - 2;
        f16x8 v = f16x8_zero();
        if ((unsigned)gy < 128u && (unsigned)gx < 127u)
            v = *(const f16x8*)(s1cl + ((((size_t)f << 14) + (gy << 7) + gx) << 2));
        *(f16x8*)&lds[(r * 136 + 2 * u) * 4] = v;
    }
    __syncthreads();

    #pragma unroll
    for (int i = 0; i < 4; ++i) {
        int ct = w * 4 + i;
        int ly = ct >> 1, hx = ct & 1;
        int px = hx * 32 + (lane & 31);
        int base = (2 * ly) * 1088 + (2 * px) * 8 + g * 16;

        f32x16 acc;
        #pragma unroll
        for (int r = 0; r < 16; ++r) acc[r] = 0.f;

        #pragma unroll
        for (int q = 0; q < 12; ++q) {
            f16x8 bv = *(const f16x8*)((const char*)lds + base +
                                       ((q >> 1) * 1088 + (q & 1) * 32));
            acc = __builtin_amdgcn_mfma_f32_32x32x16_f16(wf[q], bv, acc, 0, 0, 0);
        }

        float mA = fmaxf(fmaxf(fmaxf(acc[0], acc[1]), fmaxf(acc[2], acc[3])) + bA, 0.f);
        float mB = fmaxf(fmaxf(fmaxf(acc[4], acc[5]), fmaxf(acc[6], acc[7])) + bB, 0.f);

        int pix = ((y0 + ly) << 6) + px;
        _Float16* dst = s2cl + ((((size_t)f << 12) + pix) << 2);
        dst[g]     = (_Float16)mA;
        dst[g + 2] = (_Float16)mB;
    }
}

// ---------------------------------------------------------------------------
// k3: conv 4->32 gate precompute, MFMA. s2cl -> xg f16 in C-fragment layout
//     xg[tl][lane][16] f16, PRE-BIASED (bx+bh folded).
// block: 1 img x 8 rows. LDS: 12 rows x 72 cols x 4ch f16.
// ---------------------------------------------------------------------------
__global__ __launch_bounds__(256) void k3_mfma(
    const _Float16* __restrict__ s2cl, const _Float16* __restrict__ wxF,
    const float* __restrict__ btot, _Float16* __restrict__ xg)
{
    __shared__ _Float16 lds[12 * 72 * 4];    // pitch 576 B/row
    int tid = threadIdx.x;
    int lane = tid & 63, w = tid >> 6, g = lane >> 5;
    int f  = blockIdx.x >> 3;
    int yt = blockIdx.x & 7;
    int y0 = yt << 3;

    f16x8 wf[10];
    #pragma unroll
    for (int q = 0; q < 10; ++q)
        wf[q] = *(const f16x8*)(wxF + ((size_t)q * 64 + lane) * 8);

    float bsel[16];
    #pragma unroll
    for (int r = 0; r < 16; ++r) {
        int row0 = (r & 3) + 8 * (r >> 2);
        bsel[r] = g ? btot[row0 + 4] : btot[row0];
    }

    for (int i = tid; i < 12 * 36; i += 256) {
        int r = i / 36, u = i % 36;
        int gy = y0 - 2 + r;
        int gx = 2 * u - 2;
        f16x8 v = f16x8_zero();
        if ((unsigned)gy < 64u && (unsigned)gx < 63u)
            v = *(const f16x8*)(s2cl + ((((size_t)f << 12) + (gy << 6) + gx) << 2));
        *(f16x8*)&lds[(r * 72 + 2 * u) * 4] = v;
    }
    __syncthreads();

    #pragma unroll
    for (int i = 0; i < 4; ++i) {
        int ct = w * 4 + i;
        int ly = ct >> 1, hx = ct & 1;
        int px = hx * 32 + (lane & 31);
        int base = ly * 576 + px * 8 + g * 16;

        f32x16 acc;
        #pragma unroll
        for (int r = 0; r < 16; ++r) acc[r] = 0.f;

        #pragma unroll
        for (int q = 0; q < 10; ++q) {
            f16x8 bv = *(const f16x8*)((const char*)lds + base +
                                       ((q >> 1) * 576 + (q & 1) * 32));
            acc = __builtin_amdgcn_mfma_f32_32x32x16_f16(wf[q], bv, acc, 0, 0, 0);
        }

        size_t tl = (size_t)f * 128 + (y0 + ly) * 2 + hx;
        f16x8 lo, hi;
        #pragma unroll
        for (int r = 0; r < 8; ++r) {
            lo[r] = (_Float16)(acc[r] + bsel[r]);
            hi[r] = (_Float16)(acc[r + 8] + bsel[r + 8]);
        }
        _Float16* dst = xg + tl * 1024 + lane * 16;
        *(f16x8*)dst       = lo;
        *(f16x8*)(dst + 8) = hi;
    }
}

// ---------------------------------------------------------------------------
// k4: one ConvLSTM step, MFMA + in-lane LSTM epilogue.
// block: (b, 2 rows); 4 waves, 1 col-tile each. LDS: 6 rows x 68 x 8ch f16.
// ---------------------------------------------------------------------------
__global__ __launch_bounds__(256) void k4_mfma(
    const _Float16* __restrict__ xg_t, const _Float16* __restrict__ hprev,
    const _Float16* __restrict__ whF, float* __restrict__ cbuf,
    const float* __restrict__ wci, const float* __restrict__ wcf,
    const float* __restrict__ wco, _Float16* __restrict__ hnext,
    float* __restrict__ out_hc, int last)
{
    __shared__ _Float16 lds[6 * 68 * 8];     // pitch 1088 B/row
    int tid = threadIdx.x;
    int lane = tid & 63, w = tid >> 6, g = lane >> 5;
    int b  = blockIdx.x >> 5;
    int y0 = (blockIdx.x & 31) << 1;

    f16x8 wf[14];
    #pragma unroll
    for (int q = 0; q < 14; ++q)
        wf[q] = *(const f16x8*)(whF + ((size_t)q * 64 + lane) * 8);

    for (int i = tid; i < 6 * 68; i += 256) {
        int r = i / 68, u = i % 68;
        int gy = y0 - 2 + r;
        int gx = u - 2;
        f16x8 v = f16x8_zero();
        if ((unsigned)gy < 64u && (unsigned)gx < 64u)
            v = *(const f16x8*)(hprev + ((((size_t)b << 12) + (gy << 6) + gx) << 3));
        *(f16x8*)&lds[(r * 68 + u) * 8] = v;
    }
    __syncthreads();

    int toffs[14];
    #pragma unroll
    for (int q = 0; q < 14; ++q) {
        int t0 = 2 * q, t1 = 2 * q + 1;
        int o0 = TKY(t0) * 1088 + TKX(t0) * 16;
        int o1 = TKY(t1) * 1088 + TKX(t1) * 16;
        toffs[q] = g ? o1 : o0;
    }

    int ly = w >> 1, hx = w & 1;
    int px = hx * 32 + (lane & 31);
    size_t tl = (size_t)b * 128 + (y0 + ly) * 2 + hx;

    const f16x8* xs = (const f16x8*)(xg_t + tl * 1024 + lane * 16);
    f16x8 v0 = xs[0], v1 = xs[1];
    f32x16 acc;
    #pragma unroll
    for (int r = 0; r < 8; ++r) {
        acc[r]     = (float)v0[r];
        acc[r + 8] = (float)v1[r];
    }

    int base = ly * 1088 + px * 16;
    #pragma unroll
    for (int q = 0; q < 14; ++q) {
        f16x8 bv = *(const f16x8*)((const char*)lds + base + toffs[q]);
        acc = __builtin_amdgcn_mfma_f32_32x32x16_f16(wf[q], bv, acc, 0, 0, 0);
    }

    int pix = ((y0 + ly) << 6) + px;
    #pragma unroll
    for (int cc = 0; cc < 4; ++cc) {
        int ch = 2 * cc + g;
        size_t sidx = (((size_t)b * 8 + ch) << 12) + pix;
        int ppix = (ch << 12) + pix;
        float c_old = cbuf[sidx];
        float i_ = fast_sigmoid(acc[4 * cc + 0] + c_old * wci[ppix]);
        float f_ = fast_sigmoid(acc[4 * cc + 1] + c_old * wcf[ppix]);
        float cn = f_ * c_old + i_ * fast_tanh(acc[4 * cc + 2]);
        float o_ = fast_sigmoid(acc[4 * cc + 3] + cn * wco[ppix]);
        float hn = o_ * fast_tanh(cn);
        if (last) {
            out_hc[sidx] = hn;
            out_hc[sidx + 1048576] = cn;
        } else {
            cbuf[sidx] = cn;
            hnext[((((size_t)b << 12) + pix) << 3) + ch] = (_Float16)hn;
        }
    }
}

// ---------------------------------------------------------------------------
extern "C" void kernel_launch(void* const* d_in, const int* in_sizes, int n_in,
                              void* d_out, int out_size, void* d_ws, size_t ws_size,
                              hipStream_t stream)
{
    const float* obs = (const float*)d_in[0];
    const float* w1  = (const float*)d_in[1];
    const float* b1  = (const float*)d_in[2];
    const float* w2  = (const float*)d_in[3];
    const float* b2  = (const float*)d_in[4];
    const float* wx  = (const float*)d_in[5];
    const float* bx  = (const float*)d_in[6];
    const float* wh  = (const float*)d_in[7];
    const float* bh  = (const float*)d_in[8];
    const float* wci = (const float*)d_in[9];
    const float* wcf = (const float*)d_in[10];
    const float* wco = (const float*)d_in[11];

    char* wsb = (char*)d_ws;
    // byte layout:
    //   [0, 67,108,864)             xg f16 [32768 tl][1024]  (overlays s1cl)
    //   [0, 33,554,432)             s1cl f16 [256][16384][4] (dead after k2)
    //   [67,108,864, 75,497,472)    s2cl f16 [256][4096][4]
    //   [75,497,472, 77,594,624)    hA f16 [32][4096][8]
    //   [77,594,624, 79,691,776)    hB f16
    //   [79,691,776, 83,886,080)    cbuf f32 [32][8][4096]
    //   [83,886,080, ...)           w1T, w2F, wxF, whF, btot
    _Float16* xg   = (_Float16*)wsb;
    _Float16* s1cl = (_Float16*)wsb;
    _Float16* s2cl = (_Float16*)(wsb + 67108864);
    _Float16* hA   = (_Float16*)(wsb + 75497472);
    _Float16* hB   = (_Float16*)(wsb + 77594624);
    float*    cbuf = (float*)(wsb + 79691776);
    float*    w1T  = (float*)(wsb + 83886080);
    _Float16* w2F  = (_Float16*)(wsb + 83886592);
    _Float16* wxF  = (_Float16*)(wsb + 83898880);
    _Float16* whF  = (_Float16*)(wsb + 83909120);
    float*    btot = (float*)(wsb + 83923456);

    kT_prep<<<64, 256, 0, stream>>>(w1, w2, wx, wh, bx, bh,
                                    w1T, w2F, wxF, whF, btot);

    k1_conv_pool<<<8192, 256, 0, stream>>>(obs, w1T, b1, s1cl);
    k2_mfma     <<<2048, 256, 0, stream>>>(s1cl, w2F, b2, s2cl);
    k3_mfma     <<<2048, 256, 0, stream>>>(s2cl, wxF, btot, xg);

    hipMemsetAsync(hA,   0, 2097152, stream);
    hipMemsetAsync(cbuf, 0, 4194304, stream);

    for (int t = 0; t < 8; ++t) {
        const _Float16* hp = (t & 1) ? hB : hA;
        _Float16*       hn = (t & 1) ? hA : hB;
        k4_mfma<<<1024, 256, 0, stream>>>(
            xg + (size_t)t * 4194304, hp, whF, cbuf,
            wci, wcf, wco, hn, (float*)d_out, t == 7);
    }
}